// Round 9
// baseline (97.666 us; speedup 1.0000x reference)
//
#include <hip/hip_runtime.h>

#define BN_EPS 1e-5f
#define QR_IMG   73984      // 34*34*64 bytes per (kc, image)
#define QR_KC    2367488    // 32 * QR_IMG
#define QR_ROWB  2176       // 34 slots * 64B
#define SR_STEP  16384      // per (t,kc): 256 o * 64B

typedef __attribute__((ext_vector_type(4))) int int32x4;

// ---------------------------------------------------------------------------
// Weight prep (both layers in one launch): grid 512; set = blockIdx.x>>8.
// alpha[o] = mean|w[o]| ; Sr[(t*4+kc)*256 + o][64] = sign i8.
// ---------------------------------------------------------------------------
__global__ void prep_w_kernel(const float* __restrict__ w1,
                              signed char* __restrict__ Sr1,
                              float* __restrict__ alpha1,
                              const float* __restrict__ w2,
                              signed char* __restrict__ Sr2,
                              float* __restrict__ alpha2) {
    int set = blockIdx.x >> 8;
    const float* w = set ? w2 : w1;
    signed char* Sr = set ? Sr2 : Sr1;
    float* alpha = set ? alpha2 : alpha1;
    int o = blockIdx.x & 255;
    int c = threadIdx.x;  // 256
    const float* wp = w + (o * 256 + c) * 9;
    float s = 0.f;
    __shared__ __align__(16) signed char lsg[9][256];
    __shared__ float red[256];
#pragma unroll
    for (int j = 0; j < 9; ++j) {
        float v = wp[j];
        s += fabsf(v);
        lsg[j][c] = v > 0.f ? 1 : (v < 0.f ? -1 : 0);
    }
    red[c] = s;
    __syncthreads();
    for (int off = 128; off > 0; off >>= 1) {
        if (c < off) red[c] += red[c + off];
        __syncthreads();
    }
    if (c == 0) alpha[o] = red[0] / 2304.0f;
    if (c < 144) {
        int t = c / 16, u = c % 16;
        int c0 = u * 16;
        int kc = c0 >> 6, cb = c0 & 63;
        int32x4 v = *(const int32x4*)(&lsg[t][c0]);
        *(int32x4*)(Sr + (size_t)((t * 4 + kc) * 256 + o) * 64 + cb) = v;
    }
}

// ---------------------------------------------------------------------------
// partials[bid] = block-sum of |bn1(x)| (deterministic tree).
// ---------------------------------------------------------------------------
__global__ void bnabs_reduce_kernel(const float* __restrict__ x,
                                    const float* __restrict__ gamma,
                                    const float* __restrict__ beta,
                                    const float* __restrict__ mean,
                                    const float* __restrict__ var,
                                    float* __restrict__ partials) {
    int tid = blockIdx.x * blockDim.x + threadIdx.x;
    int nthreads = gridDim.x * blockDim.x;
    const float4* x4 = (const float4*)x;
    float s = 0.f;
    for (int i = tid; i < 2097152; i += nthreads) {
        int c = (i >> 8) & 255;
        float inv = gamma[c] * rsqrtf(var[c] + BN_EPS);
        float b = beta[c] - mean[c] * inv;
        float4 v = x4[i];
        s += fabsf(v.x * inv + b) + fabsf(v.y * inv + b) +
             fabsf(v.z * inv + b) + fabsf(v.w * inv + b);
    }
    __shared__ float red[256];
    red[threadIdx.x] = s;
    __syncthreads();
    for (int off = 128; off > 0; off >>= 1) {
        if (threadIdx.x < off) red[threadIdx.x] += red[threadIdx.x + off];
        __syncthreads();
    }
    if (threadIdx.x == 0) partials[blockIdx.x] = red[0];
}

__global__ void finalize_delta_kernel(const float* __restrict__ partials, int n,
                                      float scale, float* __restrict__ out) {
    __shared__ float red[256];
    float s = 0.f;
    for (int i = threadIdx.x; i < n; i += 256) s += partials[i];
    red[threadIdx.x] = s;
    __syncthreads();
    for (int off = 128; off > 0; off >>= 1) {
        if (threadIdx.x < off) red[threadIdx.x] += red[threadIdx.x + off];
        __syncthreads();
    }
    if (threadIdx.x == 0) *out = red[0] * scale;
}

// ---------------------------------------------------------------------------
// Quantize into k-chunk-major padded layout:
// qr[kc][n][y+1][x+1][64] i8 in {-1,0,+1}; also zeroes this buffer's halo
// (each block handles 132 of the 67584 16B halo pieces).
// ---------------------------------------------------------------------------
__global__ __launch_bounds__(256) void quant_kernel(
    const float* __restrict__ src,
    const float* __restrict__ gamma, const float* __restrict__ beta,
    const float* __restrict__ mean, const float* __restrict__ var,
    const float* __restrict__ deltaPtr, signed char* __restrict__ qr) {
    __shared__ float sInv[256], sB[256];
    int tid = threadIdx.x;
    {
        float inv = gamma[tid] * rsqrtf(var[tid] + BN_EPS);
        sInv[tid] = inv;
        sB[tid] = beta[tid] - mean[tid] * inv;
    }
    int bid = blockIdx.x;          // 512 = 32 n * 16 pblk
    // ---- halo zero: pieces [bid*132, bid*132+132) of 67584 ----
    {
        int32x4 z; z[0] = 0; z[1] = 0; z[2] = 0; z[3] = 0;
        int base = bid * 132;
        for (int k = tid; k < 132; k += 256) {
            int idx = base + k;
            int sub = idx & 3;
            int rest = idx >> 2;        // 0..16895
            int s = rest % 132;
            int r2 = rest / 132;        // 0..127
            int hn = r2 & 31;
            int hkc = r2 >> 5;
            int r, cc;
            if (s < 34)       { r = 0;        cc = s; }
            else if (s < 68)  { r = 33;       cc = s - 34; }
            else if (s < 100) { r = s - 67;   cc = 0; }
            else              { r = s - 99;   cc = 33; }
            *(int32x4*)(qr + (size_t)hkc * QR_KC + (size_t)hn * QR_IMG +
                        (size_t)(r * 34 + cc) * 64 + sub * 16) = z;
        }
    }
    __syncthreads();
    int n = bid >> 4;
    int p0 = (bid & 15) * 64;
    int l = tid & 63, wv = tid >> 6;   // wv == kc
    int p = p0 + l;
    int y = p >> 5, x = p & 31;
    float delta = *deltaPtr;
    const float* sp = src + (size_t)n * 262144 + p;
    signed char* qp = qr + (size_t)wv * QR_KC + (size_t)n * QR_IMG +
                      (size_t)((y + 1) * 34 + (x + 1)) * 64;
#pragma unroll
    for (int kg = 0; kg < 4; ++kg) {
        int w4[4];
#pragma unroll
        for (int d = 0; d < 4; ++d) {
            int wrd = 0;
#pragma unroll
            for (int j = 0; j < 4; ++j) {
                int c = wv * 64 + kg * 16 + d * 4 + j;
                float s = sp[c * 1024] * sInv[c] + sB[c];
                int qv = s > delta ? 1 : (s < -delta ? -1 : 0);
                wrd |= (qv & 255) << (8 * j);
            }
            w4[d] = wrd;
        }
        int32x4 vv;
        vv[0] = w4[0]; vv[1] = w4[1]; vv[2] = w4[2]; vv[3] = w4[3];
        *(int32x4*)(qp + kg * 16) = vv;
    }
}

// ---------------------------------------------------------------------------
// TBN conv: i8 MFMA 16x16x64. 512 blocks x 4 waves (2x2); block 128o x 128px,
// wave 64o x 64px: per step 4 A global loads + 4 B ds_reads + 16 MFMA ->
// LDS (384cyc) and VMEM (512cyc) both under the 652cyc MFMA budget.
// B reg-staged into swizzled LDS per kc (lgkm-only barriers, no vmcnt drain);
// A from L2-hot Sr via 3-deep asm ring, exact counted vmcnt.
// ---------------------------------------------------------------------------
template <bool FUSE>
__global__ __launch_bounds__(256, 2) void tbn_conv_kernel(
    const signed char* __restrict__ qr,   // [4][32][34][34][64] i8
    const signed char* __restrict__ Sr,   // [t*4+kc][256][64] i8
    const float* __restrict__ alpha,      // [256]
    const float* __restrict__ resid,      // [32][256][1024] f32
    float* __restrict__ out,              // [32][256][1024] f32
    const float* __restrict__ gamma, const float* __restrict__ beta,
    const float* __restrict__ mean, const float* __restrict__ var,
    float* __restrict__ partials) {
    __shared__ __align__(16) signed char Bl[13056];  // [6 rows][34 slots][64] swz
    __shared__ float sAl[128], sInvS[128], sBS[128];
    __shared__ float red[256];

    int bid = blockIdx.x;
    int wg = (bid & 7) * 64 + (bid >> 3);  // bijective, 512 % 8 == 0
    int n = wg >> 4;
    int pb = (wg >> 1) & 7;
    int ob = wg & 1;
    int tid = threadIdx.x, lane = tid & 63, wid = tid >> 6;
    int l15 = lane & 15, kg = lane >> 4;
    int wr = wid >> 1, wc = wid & 1;

    if (tid < 128) {
        int o = ob * 128 + tid;
        sAl[tid] = alpha[o];
        if (FUSE) {
            float inv = gamma[o] * rsqrtf(var[o] + BN_EPS);
            sInvS[tid] = inv;
            sBS[tid] = beta[o] - mean[o] * inv;
        }
    }
    __syncthreads();

    int o0 = ob * 128 + wr * 64;
    int y0 = pb * 4;  // first padded row of the 6-row B window

    const signed char* Abase = Sr + (size_t)(o0 + l15) * 64 + kg * 16;
    const signed char* gsrcBase = qr + (size_t)n * QR_IMG + (size_t)y0 * QR_ROWB;

    // stage offsets: 816 x 16B pieces, 4 per thread (clamped dup at tail)
    int stSrc[4], stDst[4];
#pragma unroll
    for (int k = 0; k < 4; ++k) {
        int idx = tid + 256 * k; if (idx > 815) idx = 815;
        int byte = idx * 16;
        int row = byte / 2176;
        int rem = byte - row * 2176;
        int slot = rem >> 6;
        int kgp = (rem >> 4) & 3;
        stSrc[k] = byte;
        stDst[k] = row * 2176 + slot * 64 + (((kgp + (slot >> 1)) & 3) << 4);
    }

    int32x4 acc[4][4];
#pragma unroll
    for (int m = 0; m < 4; ++m)
#pragma unroll
        for (int nn = 0; nn < 4; ++nn) {
            acc[m][nn][0] = 0; acc[m][nn][1] = 0;
            acc[m][nn][2] = 0; acc[m][nn][3] = 0;
        }

    int32x4 fa[3][4], fb[2][4], stReg[4];

#define GLD(D, P) \
    asm volatile("global_load_dwordx4 %0, %1, off" : "=v"(D) : "v"(P))
#define SLAB(I) ((((I) % 9) * 4) + ((I) / 9))
#define LOADA(I)                                                              \
    do {                                                                      \
        const signed char* pa_ = Abase + (size_t)SLAB(I) * SR_STEP;           \
        GLD(fa[(I) % 3][0], pa_);                                             \
        GLD(fa[(I) % 3][1], pa_ + 1024);                                      \
        GLD(fa[(I) % 3][2], pa_ + 2048);                                      \
        GLD(fa[(I) % 3][3], pa_ + 3072);                                      \
    } while (0)
#define STAGE_ISSUE(KC)                                                       \
    do {                                                                      \
        const signed char* g_ = gsrcBase + (size_t)(KC) * QR_KC;              \
        GLD(stReg[0], g_ + stSrc[0]);                                         \
        GLD(stReg[1], g_ + stSrc[1]);                                         \
        GLD(stReg[2], g_ + stSrc[2]);                                         \
        GLD(stReg[3], g_ + stSrc[3]);                                         \
    } while (0)
#define STAGE_WRITE()                                                         \
    do {                                                                      \
        *(int32x4*)(&Bl[stDst[0]]) = stReg[0];                                \
        *(int32x4*)(&Bl[stDst[1]]) = stReg[1];                                \
        *(int32x4*)(&Bl[stDst[2]]) = stReg[2];                                \
        *(int32x4*)(&Bl[stDst[3]]) = stReg[3];                                \
    } while (0)
#define LOADB(T, BUF)                                                         \
    do {                                                                      \
        _Pragma("unroll")                                                     \
        for (int nn = 0; nn < 4; ++nn) {                                      \
            const int kh_ = (T) / 3 - 1, kw_ = (T) % 3 - 1;                   \
            const int row_ = wc * 2 + (nn >> 1) + 1 + kh_;                    \
            int slot_ = (nn & 1) * 16 + l15 + 1 + kw_;                        \
            int off_ = row_ * 2176 + slot_ * 64 +                             \
                       (((kg + (slot_ >> 1)) & 3) << 4);                      \
            fb[BUF][nn] = *(const int32x4*)(&Bl[off_]);                       \
        }                                                                     \
    } while (0)
#define MFMA16(I, BUF)                                                        \
    do {                                                                      \
        _Pragma("unroll")                                                     \
        for (int m = 0; m < 4; ++m)                                           \
            _Pragma("unroll")                                                 \
            for (int nn = 0; nn < 4; ++nn)                                    \
                acc[m][nn] = __builtin_amdgcn_mfma_i32_16x16x64_i8(           \
                    fa[(I) % 3][m], fb[BUF][nn], acc[m][nn], 0, 0, 0);        \
    } while (0)
#define WAITV(N)                                                              \
    do { asm volatile("s_waitcnt vmcnt(" #N ")" ::: "memory");                \
         __builtin_amdgcn_sched_barrier(0); } while (0)
#define WAITL()                                                               \
    do { asm volatile("s_waitcnt lgkmcnt(0)" ::: "memory");                   \
         __builtin_amdgcn_sched_barrier(0); } while (0)
#define BAR()                                                                 \
    do { __builtin_amdgcn_s_barrier();                                        \
         __builtin_amdgcn_sched_barrier(0); } while (0)

    // prologue: stage kc=0, prime A ring, publish Bl
    STAGE_ISSUE(0);
    LOADA(0); LOADA(1); LOADA(2);
    WAITV(12);           // retires the 4 stage loads (A0..A2 stay in flight)
    STAGE_WRITE();
    WAITL();
    BAR();
    LOADB(0, 0);

    // FIFO-exact vmcnt: retire A(i) each step.
    //   steady (3-deep, no stage in flight): N = 8
    //   stage(kc+1) in flight (i = kc*9 + {1,2}, kc<3): N = 12
    //   t==3 retires stage + A(i) via N = 8
    //   tail: i==34 -> 4, i==35 -> 0
#pragma unroll
    for (int i = 0; i < 36; ++i) {
        const int kc = i / 9, t = i % 9;
        if (i == 1 || i == 2 || i == 10 || i == 11 || i == 19 || i == 20) {
            WAITV(12);
        } else if (i == 34) { WAITV(4); }
        else if (i == 35)   { WAITV(0); }
        else                { WAITV(8); }
        if (t == 0 && kc < 3) STAGE_ISSUE(kc + 1);
        if (t < 8) LOADB(t + 1, (t + 1) & 1);
        MFMA16(i, t & 1);
        if (i + 3 <= 35) LOADA(i + 3);
        if (t == 8 && kc < 3) {
            WAITL();
            BAR();            // all waves done reading Bl (lgkm only)
            STAGE_WRITE();    // stage regs were retired at t==3's wait
            WAITL();
            BAR();            // writes visible
            LOADB(0, 0);
        }
    }
#undef GLD
#undef SLAB
#undef LOADA
#undef STAGE_ISSUE
#undef STAGE_WRITE
#undef LOADB
#undef MFMA16
#undef WAITV
#undef WAITL
#undef BAR

    // D layout: col = l15 (pixel), row = kg*4 + r (o within 16)
    float psum = 0.f;
#pragma unroll
    for (int m = 0; m < 4; ++m) {
#pragma unroll
        for (int r = 0; r < 4; ++r) {
            int oLoc = wr * 64 + m * 16 + kg * 4 + r;  // 0..127
            int o = ob * 128 + oLoc;
            float al = sAl[oLoc];
            float inv = 0.f, bb = 0.f;
            if (FUSE) { inv = sInvS[oLoc]; bb = sBS[oLoc]; }
            const float* rp = resid + (size_t)n * 262144 + (size_t)o * 1024;
            float* op = out + (size_t)n * 262144 + (size_t)o * 1024;
#pragma unroll
            for (int nn = 0; nn < 4; ++nn) {
                int p = pb * 128 + wc * 64 + nn * 16 + l15;
                float hv = rp[p] + al * (float)acc[m][nn][r];
                op[p] = hv;
                if (FUSE) psum += fabsf(hv * inv + bb);
            }
        }
    }
    if (FUSE) {
        red[tid] = psum;
        __syncthreads();
        for (int off = 128; off > 0; off >>= 1) {
            if (tid < off) red[tid] += red[tid + off];
            __syncthreads();
        }
        if (tid == 0) partials[wg] = red[0];
    }
}

// ---------------------------------------------------------------------------
extern "C" void kernel_launch(void* const* d_in, const int* in_sizes, int n_in,
                              void* d_out, int out_size, void* d_ws, size_t ws_size,
                              hipStream_t stream) {
    (void)in_sizes; (void)n_in; (void)out_size; (void)ws_size;
    const float* x  = (const float*)d_in[0];
    const float* w1 = (const float*)d_in[1];
    const float* w2 = (const float*)d_in[2];
    const float* g1 = (const float*)d_in[3];
    const float* b1 = (const float*)d_in[4];
    const float* m1 = (const float*)d_in[5];
    const float* v1 = (const float*)d_in[6];
    const float* g2 = (const float*)d_in[7];
    const float* b2 = (const float*)d_in[8];
    const float* m2 = (const float*)d_in[9];
    const float* v2 = (const float*)d_in[10];
    float* out = (float*)d_out;
    char* ws = (char*)d_ws;

    float* delta1 = (float*)(ws + 0);
    float* delta2 = (float*)(ws + 4);
    float* red1   = (float*)(ws + 4096);       // 4096 floats
    float* redc   = (float*)(ws + 20480);      // 512 floats
    float* alpha1 = (float*)(ws + 24576);
    float* alpha2 = (float*)(ws + 25600);
    signed char* Sr1 = (signed char*)(ws + ((size_t)1 << 20));
    signed char* Sr2 = (signed char*)(ws + ((size_t)2 << 20));
    signed char* qr1 = (signed char*)(ws + ((size_t)4 << 20));   // 9.5 MB
    signed char* qr2 = (signed char*)(ws + ((size_t)16 << 20));  // 9.5 MB
    float* h         = (float*)(ws + ((size_t)28 << 20));        // 134 MB

    const float kScale = 0.7f / 8388608.0f;

    prep_w_kernel<<<512, 256, 0, stream>>>(w1, Sr1, alpha1, w2, Sr2, alpha2);
    bnabs_reduce_kernel<<<4096, 256, 0, stream>>>(x, g1, b1, m1, v1, red1);
    finalize_delta_kernel<<<1, 256, 0, stream>>>(red1, 4096, kScale, delta1);
    quant_kernel<<<512, 256, 0, stream>>>(x, g1, b1, m1, v1, delta1, qr1);
    tbn_conv_kernel<true><<<512, 256, 0, stream>>>(qr1, Sr1, alpha1, x, h,
                                                   g2, b2, m2, v2, redc);
    finalize_delta_kernel<<<1, 256, 0, stream>>>(redc, 512, kScale, delta2);
    quant_kernel<<<512, 256, 0, stream>>>(h, g2, b2, m2, v2, delta2, qr2);
    tbn_conv_kernel<false><<<512, 256, 0, stream>>>(qr2, Sr2, alpha2, h, out,
                                                    nullptr, nullptr, nullptr,
                                                    nullptr, nullptr);
}

// Round 10
// 85.440 us; speedup vs baseline: 1.1431x; 1.1431x over previous
//
#include <hip/hip_runtime.h>

#define BN_EPS 1e-5f
#define SR_STEP  16384      // per (t,kc): 256 o * 64B
#define BQ_KC    13056      // 6 rows * 34 slots * 64B per kc
#define KSCALE   (0.7f / 8388608.0f)

typedef __attribute__((ext_vector_type(4))) int int32x4;

// ---------------------------------------------------------------------------
// Weight prep (both layers, one launch): grid 512; set = blockIdx.x>>8.
// alpha[o] = mean|w[o]| ; Sr[(t*4+kc)*256 + o][64] = sign i8.
// ---------------------------------------------------------------------------
__global__ void prep_w_kernel(const float* __restrict__ w1,
                              signed char* __restrict__ Sr1,
                              float* __restrict__ alpha1,
                              const float* __restrict__ w2,
                              signed char* __restrict__ Sr2,
                              float* __restrict__ alpha2) {
    int set = blockIdx.x >> 8;
    const float* w = set ? w2 : w1;
    signed char* Sr = set ? Sr2 : Sr1;
    float* alpha = set ? alpha2 : alpha1;
    int o = blockIdx.x & 255;
    int c = threadIdx.x;  // 256
    const float* wp = w + (o * 256 + c) * 9;
    float s = 0.f;
    __shared__ __align__(16) signed char lsg[9][256];
    __shared__ float red[256];
#pragma unroll
    for (int j = 0; j < 9; ++j) {
        float v = wp[j];
        s += fabsf(v);
        lsg[j][c] = v > 0.f ? 1 : (v < 0.f ? -1 : 0);
    }
    red[c] = s;
    __syncthreads();
    for (int off = 128; off > 0; off >>= 1) {
        if (c < off) red[c] += red[c + off];
        __syncthreads();
    }
    if (c == 0) alpha[o] = red[0] / 2304.0f;
    if (c < 144) {
        int t = c / 16, u = c % 16;
        int c0 = u * 16;
        int kc = c0 >> 6, cb = c0 & 63;
        int32x4 v = *(const int32x4*)(&lsg[t][c0]);
        *(int32x4*)(Sr + (size_t)((t * 4 + kc) * 256 + o) * 64 + cb) = v;
    }
}

// ---------------------------------------------------------------------------
// partials[bid] = block-sum of |bn1(x)| (deterministic tree).
// ---------------------------------------------------------------------------
__global__ void bnabs_reduce_kernel(const float* __restrict__ x,
                                    const float* __restrict__ gamma,
                                    const float* __restrict__ beta,
                                    const float* __restrict__ mean,
                                    const float* __restrict__ var,
                                    float* __restrict__ partials) {
    int tid = blockIdx.x * blockDim.x + threadIdx.x;
    int nthreads = gridDim.x * blockDim.x;
    const float4* x4 = (const float4*)x;
    float s = 0.f;
    for (int i = tid; i < 2097152; i += nthreads) {
        int c = (i >> 8) & 255;
        float inv = gamma[c] * rsqrtf(var[c] + BN_EPS);
        float b = beta[c] - mean[c] * inv;
        float4 v = x4[i];
        s += fabsf(v.x * inv + b) + fabsf(v.y * inv + b) +
             fabsf(v.z * inv + b) + fabsf(v.w * inv + b);
    }
    __shared__ float red[256];
    red[threadIdx.x] = s;
    __syncthreads();
    for (int off = 128; off > 0; off >>= 1) {
        if (threadIdx.x < off) red[threadIdx.x] += red[threadIdx.x + off];
        __syncthreads();
    }
    if (threadIdx.x == 0) partials[blockIdx.x] = red[0];
}

// ---------------------------------------------------------------------------
// Fused TBN conv: quantization done in-block (prologue) into LDS, then
// i8 MFMA 16x16x64 over 36 (kc,t) steps with a barrier-free main loop:
// only the 3-deep A-register ring lives in the vmcnt FIFO (exact counts).
// 512 blocks x 4 waves (2x2); block 128o x 128px, wave 64o x 64px.
// Epilogue: out = resid + alpha*acc (+ fused partial of sum|bn_next(out)|).
// ---------------------------------------------------------------------------
template <bool FUSE>
__global__ __launch_bounds__(256, 2) void tbn_conv_kernel(
    const float* __restrict__ src,        // quant source AND residual (NCHW)
    const signed char* __restrict__ Sr,   // [t*4+kc][256][64] i8
    const float* __restrict__ alpha,      // [256]
    float* __restrict__ out,              // [32][256][1024] f32
    const float* __restrict__ dpart, int nPart,  // delta partials
    const float* __restrict__ qg, const float* __restrict__ qb,
    const float* __restrict__ qm, const float* __restrict__ qv,   // own BN
    const float* __restrict__ fg, const float* __restrict__ fbt,
    const float* __restrict__ fm, const float* __restrict__ fv,   // next BN
    float* __restrict__ partials) {
    __shared__ __align__(16) signed char Bq[4 * BQ_KC];  // 52224 B
    __shared__ float sInv[256], sB[256];
    __shared__ float sAl[128], sInvS[128], sBS[128];
    __shared__ float red[256];

    int bid = blockIdx.x;
    int wg = (bid & 7) * 64 + (bid >> 3);  // bijective, 512 % 8 == 0
    int n = wg >> 4;
    int pb = (wg >> 1) & 7;
    int ob = wg & 1;
    int tid = threadIdx.x, lane = tid & 63, wid = tid >> 6;
    int l15 = lane & 15, kg = lane >> 4;
    int wr = wid >> 1, wc = wid & 1;
    int y0 = pb * 4;

    // ---- prologue A: BN params + delta partial sums ----
    {
        float inv = qg[tid] * rsqrtf(qv[tid] + BN_EPS);
        sInv[tid] = inv;
        sB[tid] = qb[tid] - qm[tid] * inv;
    }
    if (tid < 128) {
        int o = ob * 128 + tid;
        sAl[tid] = alpha[o];
        if (FUSE) {
            float inv = fg[o] * rsqrtf(fv[o] + BN_EPS);
            sInvS[tid] = inv;
            sBS[tid] = fbt[o] - fm[o] * inv;
        }
    }
    float s = 0.f;
    for (int i = tid; i < nPart; i += 256) s += dpart[i];
    red[tid] = s;
    __syncthreads();
    for (int off = 128; off > 0; off >>= 1) {
        if (tid < off) red[tid] += red[tid + off];
        __syncthreads();
    }
    float delta = red[0] * KSCALE;

    // ---- prologue B: quantize this block's 6x34x256 window into Bq ----
    // interior: 768 quad-pieces = 3 * 256; piece = 4 px x 16 ch -> 4 x 16B
    const float4* src4 = (const float4*)src + (size_t)n * 65536;
#pragma unroll
    for (int k = 0; k < 3; ++k) {
        int idx = tid + 256 * k;
        int quad = idx & 7;          // 4-px group within row
        int cg = (idx >> 3) & 15;    // 16-channel group
        int row = idx >> 7;          // 0..5 (padded window row)
        int absrow = y0 + row - 1;
        int wrd[4][4];
#pragma unroll
        for (int px = 0; px < 4; ++px)
#pragma unroll
            for (int d = 0; d < 4; ++d) wrd[px][d] = 0;
        if (absrow >= 0 && absrow < 32) {
#pragma unroll
            for (int j = 0; j < 16; ++j) {
                int c = cg * 16 + j;
                float4 v = src4[(size_t)c * 256 + absrow * 8 + quad];
                float inv = sInv[c], bb = sB[c];
                float va[4] = {v.x, v.y, v.z, v.w};
#pragma unroll
                for (int px = 0; px < 4; ++px) {
                    float t = va[px] * inv + bb;
                    int q = t > delta ? 1 : (t < -delta ? -1 : 0);
                    wrd[px][j >> 2] |= (q & 255) << (8 * (j & 3));
                }
            }
        }
        int kc = cg >> 2, kgp = cg & 3;
#pragma unroll
        for (int px = 0; px < 4; ++px) {
            int slot = quad * 4 + px + 1;
            int dst = kc * BQ_KC + row * 2176 + slot * 64 +
                      (((kgp + (slot >> 1)) & 3) << 4);
            int32x4 vv;
            vv[0] = wrd[px][0]; vv[1] = wrd[px][1];
            vv[2] = wrd[px][2]; vv[3] = wrd[px][3];
            *(int32x4*)(&Bq[dst]) = vv;
        }
    }
    // halo columns (slot 0 and 33): 192 zero pieces
    if (tid < 192) {
        int cg = tid & 15;
        int rest = tid >> 4;         // 0..11
        int row = rest >> 1, side = rest & 1;
        int slot = side ? 33 : 0;
        int kc = cg >> 2, kgp = cg & 3;
        int dst = kc * BQ_KC + row * 2176 + slot * 64 +
                  (((kgp + (slot >> 1)) & 3) << 4);
        int32x4 z; z[0] = 0; z[1] = 0; z[2] = 0; z[3] = 0;
        *(int32x4*)(&Bq[dst]) = z;
    }
    __syncthreads();   // drains x loads + Bq writes; Bq read-only hereafter

    // ---- main loop: barrier-free, A-ring only in vmcnt FIFO ----
    int o0 = ob * 128 + wr * 64;
    const signed char* Abase = Sr + (size_t)(o0 + l15) * 64 + kg * 16;

    int32x4 acc[4][4];
#pragma unroll
    for (int m = 0; m < 4; ++m)
#pragma unroll
        for (int nn = 0; nn < 4; ++nn) {
            acc[m][nn][0] = 0; acc[m][nn][1] = 0;
            acc[m][nn][2] = 0; acc[m][nn][3] = 0;
        }

    int32x4 fa[3][4], fb[2][4];

#define GLD(D, P) \
    asm volatile("global_load_dwordx4 %0, %1, off" : "=v"(D) : "v"(P))
#define SLAB(I) ((((I) % 9) * 4) + ((I) / 9))
#define LOADA(I)                                                              \
    do {                                                                      \
        const signed char* pa_ = Abase + (size_t)SLAB(I) * SR_STEP;           \
        GLD(fa[(I) % 3][0], pa_);                                             \
        GLD(fa[(I) % 3][1], pa_ + 1024);                                      \
        GLD(fa[(I) % 3][2], pa_ + 2048);                                      \
        GLD(fa[(I) % 3][3], pa_ + 3072);                                      \
    } while (0)
#define LOADB(J, BUF)                                                         \
    do {                                                                      \
        const int kcj_ = (J) / 9, tj_ = (J) % 9;                              \
        const int kh_ = tj_ / 3 - 1, kw_ = tj_ % 3 - 1;                       \
        _Pragma("unroll")                                                     \
        for (int nn = 0; nn < 4; ++nn) {                                      \
            const int row_ = wc * 2 + (nn >> 1) + 1 + kh_;                    \
            int slot_ = (nn & 1) * 16 + l15 + 1 + kw_;                        \
            int off_ = kcj_ * BQ_KC + row_ * 2176 + slot_ * 64 +              \
                       (((kg + (slot_ >> 1)) & 3) << 4);                      \
            fb[BUF][nn] = *(const int32x4*)(&Bq[off_]);                       \
        }                                                                     \
    } while (0)
#define MFMA16(I, BUF)                                                        \
    do {                                                                      \
        _Pragma("unroll")                                                     \
        for (int m = 0; m < 4; ++m)                                           \
            _Pragma("unroll")                                                 \
            for (int nn = 0; nn < 4; ++nn)                                    \
                acc[m][nn] = __builtin_amdgcn_mfma_i32_16x16x64_i8(           \
                    fa[(I) % 3][m], fb[BUF][nn], acc[m][nn], 0, 0, 0);        \
    } while (0)
#define WAITV(N)                                                              \
    do { asm volatile("s_waitcnt vmcnt(" #N ")" ::: "memory");                \
         __builtin_amdgcn_sched_barrier(0); } while (0)

    LOADA(0); LOADA(1); LOADA(2);
    LOADB(0, 0);
    // FIFO-exact: outstanding before wait at step i = {A(i),A(i+1),A(i+2)};
    // retire A(i): N=8 for i<=33, N=4 at 34, N=0 at 35.
#pragma unroll
    for (int i = 0; i < 36; ++i) {
        if (i <= 33)      WAITV(8);
        else if (i == 34) WAITV(4);
        else              WAITV(0);
        if (i < 35) LOADB(i + 1, (i + 1) & 1);
        MFMA16(i, i & 1);
        if (i + 3 <= 35) LOADA(i + 3);
    }
#undef GLD
#undef SLAB
#undef LOADA
#undef LOADB
#undef MFMA16
#undef WAITV

    // ---- epilogue: D col = l15 (pixel), row = kg*4 + r ----
    float psum = 0.f;
#pragma unroll
    for (int m = 0; m < 4; ++m) {
#pragma unroll
        for (int r = 0; r < 4; ++r) {
            int oLoc = wr * 64 + m * 16 + kg * 4 + r;  // 0..127
            int o = ob * 128 + oLoc;
            float al = sAl[oLoc];
            float inv = 0.f, bb = 0.f;
            if (FUSE) { inv = sInvS[oLoc]; bb = sBS[oLoc]; }
            const float* rp = src + (size_t)n * 262144 + (size_t)o * 1024;
            float* op = out + (size_t)n * 262144 + (size_t)o * 1024;
#pragma unroll
            for (int nn = 0; nn < 4; ++nn) {
                int p = pb * 128 + wc * 64 + nn * 16 + l15;
                float hv = rp[p] + al * (float)acc[m][nn][r];
                op[p] = hv;
                if (FUSE) psum += fabsf(hv * inv + bb);
            }
        }
    }
    if (FUSE) {
        __syncthreads();           // red[] reuse safe-guard
        red[tid] = psum;
        __syncthreads();
        for (int off = 128; off > 0; off >>= 1) {
            if (tid < off) red[tid] += red[tid + off];
            __syncthreads();
        }
        if (tid == 0) partials[wg] = red[0];
    }
}

// ---------------------------------------------------------------------------
extern "C" void kernel_launch(void* const* d_in, const int* in_sizes, int n_in,
                              void* d_out, int out_size, void* d_ws, size_t ws_size,
                              hipStream_t stream) {
    (void)in_sizes; (void)n_in; (void)out_size; (void)ws_size;
    const float* x  = (const float*)d_in[0];
    const float* w1 = (const float*)d_in[1];
    const float* w2 = (const float*)d_in[2];
    const float* g1 = (const float*)d_in[3];
    const float* b1 = (const float*)d_in[4];
    const float* m1 = (const float*)d_in[5];
    const float* v1 = (const float*)d_in[6];
    const float* g2 = (const float*)d_in[7];
    const float* b2 = (const float*)d_in[8];
    const float* m2 = (const float*)d_in[9];
    const float* v2 = (const float*)d_in[10];
    float* out = (float*)d_out;
    char* ws = (char*)d_ws;

    float* red1   = (float*)(ws + 4096);       // 4096 floats
    float* redc   = (float*)(ws + 24576);      // 512 floats
    float* alpha1 = (float*)(ws + 28672);
    float* alpha2 = (float*)(ws + 29696);
    signed char* Sr1 = (signed char*)(ws + ((size_t)1 << 20));
    signed char* Sr2 = (signed char*)(ws + ((size_t)2 << 20));
    float* h         = (float*)(ws + ((size_t)4 << 20));   // 134 MB

    prep_w_kernel<<<512, 256, 0, stream>>>(w1, Sr1, alpha1, w2, Sr2, alpha2);
    bnabs_reduce_kernel<<<4096, 256, 0, stream>>>(x, g1, b1, m1, v1, red1);
    tbn_conv_kernel<true><<<512, 256, 0, stream>>>(
        x, Sr1, alpha1, h, red1, 4096,
        g1, b1, m1, v1, g2, b2, m2, v2, redc);
    tbn_conv_kernel<false><<<512, 256, 0, stream>>>(
        h, Sr2, alpha2, out, redc, 512,
        g2, b2, m2, v2, g2, b2, m2, v2, redc);
}